// Round 10
// baseline (160.129 us; speedup 1.0000x reference)
//
#include <hip/hip_runtime.h>
#include <hip/hip_bf16.h>

#define NB 8
#define MN 50000
#define FI 32
#define FO 32
#define NE 800000
#define CAPLOG 6          // 64 slots/row; P(Poisson(16) > 64) ~ 1e-19 per row
#define CAP 64
#define FB_THREADS 200000 // 4 edges per thread; 4*200000 == NE exactly
#define FB_BLOCKS 782     // ceil(200000/256)
#define GEMM_BLOCKS 25000 // 3125 m-tiles * 8 batches

// ---------------- fused kernel: edge binning (blocks 0..781) + gemm (rest) ---------
// fill part is bound by device-scope atomic/scatter throughput (~61us; invariant to
// thread count R5/R7 and to cursor padding R9 -- padding REGRESSED, compact cursor
// keeps 3125 hot lines resident). gemm co-resides in fill's wait bubbles (R8: fused
// ~65-70us vs 61+15 serial). z interleaved bf16x2: u32 zb[m*128 + n*16 + j] -> one
// edge's gather = 512 B contiguous.
__global__ __launch_bounds__(256) void fused_prep(const float* __restrict__ x,
                                                  const float* __restrict__ W,
                                                  const int* __restrict__ rows,
                                                  const int* __restrict__ cols,
                                                  const float* __restrict__ vals,
                                                  int* __restrict__ cursor,
                                                  unsigned int* __restrict__ bucket,
                                                  unsigned int* __restrict__ zb) {
    int bid = blockIdx.x;
    int t   = threadIdx.x;

    if (bid < FB_BLOCKS) {
        int tid = bid * 256 + t;
        if (tid >= FB_THREADS) return;   // grid rounds to 200192; avoid double edges
#pragma unroll
        for (int k = 0; k < 4; ++k) {
            int e = tid + k * FB_THREADS;   // covers [0, NE) exactly once
            int r = rows[e];
            int p = atomicAdd(&cursor[r], 1);   // compact cursor (R9: padding hurt)
            if (p < CAP) {                  // overflow guard (never taken in practice)
                unsigned int vb = (unsigned int)__bfloat16_as_ushort(__float2bfloat16(vals[e]));
                bucket[(r << CAPLOG) + p] = (unsigned int)cols[e] | (vb << 16);
            }
        }
        return;
    }

    // ---- gemm part ----
    __shared__ float Ws[FI * FO];
    ((float4*)Ws)[t] = ((const float4*)W)[t];   // 256 * 16B = 4KB
    __syncthreads();

    int gb    = bid - FB_BLOCKS;
    int n     = gb / 3125;                  // 0..7
    int mb    = gb % 3125;
    int rowid = t >> 4;                     // 16 rows per block
    int j     = t & 15;                     // fo pair
    int m     = mb * 16 + rowid;

    const float4* xr = (const float4*)(x + ((long)n * MN + m) * FI);
    float4 xv[8];
#pragma unroll
    for (int i = 0; i < 8; ++i) xv[i] = xr[i];
    const float* xf = (const float*)xv;

    float a0 = 0.f, a1 = 0.f;
#pragma unroll
    for (int k = 0; k < FI; ++k) {
        a0 += xf[k] * Ws[k * FO + 2 * j];
        a1 += xf[k] * Ws[k * FO + 2 * j + 1];
    }
    unsigned int lo = (unsigned int)__bfloat16_as_ushort(__float2bfloat16(a0));
    unsigned int hi = (unsigned int)__bfloat16_as_ushort(__float2bfloat16(a1));
    zb[(long)m * 128 + n * 16 + j] = lo | (hi << 16);
}

// ---------------- kernel 3 (R7-proven, 61us): one row per WAVE ----------------
// Block = 256 = 4 waves = 4 rows. Lane t: n = t>>3, float4 fo-group fp = t&7.
// Per edge: broadcast packed (col,val) via __shfl, gather 8 B/lane (512 B/wave).
__global__ __launch_bounds__(256) void aggregate(const unsigned long long* __restrict__ zb2,
                                                 const int* __restrict__ cursor,
                                                 const unsigned int* __restrict__ bucket,
                                                 const float* __restrict__ bias,
                                                 float4* __restrict__ out4) {
    int lane = threadIdx.x & 63;
    int r    = blockIdx.x * 4 + (threadIdx.x >> 6);

    int cnt = cursor[r];
    cnt = cnt > CAP ? CAP : cnt;

    unsigned int mypk = bucket[(r << CAPLOG) + lane];  // whole bucket row in-register

    int n  = lane >> 3;
    int fp = lane & 7;
    float4 acc = ((const float4*)bias)[fp];

    int i = 0;
    for (; i + 8 <= cnt; i += 8) {
        unsigned int pk[8];
        unsigned long long z[8];
#pragma unroll
        for (int k = 0; k < 8; ++k) pk[k] = __shfl(mypk, i + k);
#pragma unroll
        for (int k = 0; k < 8; ++k) z[k] = zb2[((long)(pk[k] & 0xffff) << 6) + lane];
#pragma unroll
        for (int k = 0; k < 8; ++k) {
            float v = __uint_as_float(pk[k] & 0xffff0000u);
            unsigned int l = (unsigned int)z[k], h = (unsigned int)(z[k] >> 32);
            acc.x += v * __uint_as_float(l << 16);
            acc.y += v * __uint_as_float(l & 0xffff0000u);
            acc.z += v * __uint_as_float(h << 16);
            acc.w += v * __uint_as_float(h & 0xffff0000u);
        }
    }
    for (; i + 4 <= cnt; i += 4) {
        unsigned int pk[4];
        unsigned long long z[4];
#pragma unroll
        for (int k = 0; k < 4; ++k) pk[k] = __shfl(mypk, i + k);
#pragma unroll
        for (int k = 0; k < 4; ++k) z[k] = zb2[((long)(pk[k] & 0xffff) << 6) + lane];
#pragma unroll
        for (int k = 0; k < 4; ++k) {
            float v = __uint_as_float(pk[k] & 0xffff0000u);
            unsigned int l = (unsigned int)z[k], h = (unsigned int)(z[k] >> 32);
            acc.x += v * __uint_as_float(l << 16);
            acc.y += v * __uint_as_float(l & 0xffff0000u);
            acc.z += v * __uint_as_float(h << 16);
            acc.w += v * __uint_as_float(h & 0xffff0000u);
        }
    }
    for (; i < cnt; ++i) {
        unsigned int p0 = __shfl(mypk, i);
        float v0 = __uint_as_float(p0 & 0xffff0000u);
        unsigned long long z0 = zb2[((long)(p0 & 0xffff) << 6) + lane];
        unsigned int l0 = (unsigned int)z0, h0 = (unsigned int)(z0 >> 32);
        acc.x += v0 * __uint_as_float(l0 << 16);
        acc.y += v0 * __uint_as_float(l0 & 0xffff0000u);
        acc.z += v0 * __uint_as_float(h0 << 16);
        acc.w += v0 * __uint_as_float(h0 & 0xffff0000u);
    }

    out4[((long)n * MN + r) * 8 + fp] = acc;
}

extern "C" void kernel_launch(void* const* d_in, const int* in_sizes, int n_in,
                              void* d_out, int out_size, void* d_ws, size_t ws_size,
                              hipStream_t stream) {
    const float* x    = (const float*)d_in[0];
    const int*   rows = (const int*)d_in[1];
    const int*   cols = (const int*)d_in[2];
    const float* vals = (const float*)d_in[3];
    const float* W    = (const float*)d_in[4];
    const float* bias = (const float*)d_in[5];
    float4* out4 = (float4*)d_out;

    char* ws = (char*)d_ws;
    // workspace layout (bytes): zb 25.6MB | cursor 0.2MB | bucket 12.8MB = 38.6MB
    size_t off_z      = 0;
    size_t off_cursor = off_z + (size_t)MN * NB * FO * 2;
    size_t off_bucket = off_cursor + (size_t)MN * 4;

    unsigned int* zb     = (unsigned int*)(ws + off_z);
    int*          cursor = (int*)(ws + off_cursor);
    unsigned int* bucket = (unsigned int*)(ws + off_bucket);

    hipMemsetAsync(cursor, 0, (size_t)MN * 4, stream);

    fused_prep<<<FB_BLOCKS + GEMM_BLOCKS, 256, 0, stream>>>(x, W, rows, cols, vals,
                                                            cursor, bucket, zb);

    aggregate<<<MN / 4, 256, 0, stream>>>((const unsigned long long*)zb, cursor, bucket,
                                          bias, out4);
}

// Round 11
// 150.061 us; speedup vs baseline: 1.0671x; 1.0671x over previous
//
#include <hip/hip_runtime.h>
#include <hip/hip_bf16.h>

#define NB 8
#define MN 50000
#define FI 32
#define FO 32
#define NE 800000
#define CAPLOG 6          // 64 slots/row; P(Poisson(16) > 64) ~ 1e-19 per row
#define CAP 64
#define FB_THREADS 200000 // 4 edges per thread; 4*200000 == NE exactly
#define FB_BLOCKS 782     // ceil(200000/256)

// ---------------- kernel 1: gemm + cursor zeroing ----------------
// z interleaved bf16x2: u32 zb[m*128 + n*16 + j] -> one edge's gather = 512 B
// contiguous. Blocks 0..195 also zero cursor (stream order => done before fill).
__global__ __launch_bounds__(256) void gemm_xw(const float* __restrict__ x,
                                               const float* __restrict__ W,
                                               unsigned int* __restrict__ zb,
                                               int* __restrict__ cursor) {
    int bid = blockIdx.x;
    int t   = threadIdx.x;

    if (bid < 196) {
        int i = bid * 256 + t;
        if (i < MN) cursor[i] = 0;
    }

    __shared__ float Ws[FI * FO];
    ((float4*)Ws)[t] = ((const float4*)W)[t];   // 256 * 16B = 4KB
    __syncthreads();

    int n     = bid / 3125;                 // 0..7
    int mb    = bid % 3125;
    int rowid = t >> 4;                     // 16 rows per block
    int j     = t & 15;                     // fo pair
    int m     = mb * 16 + rowid;

    const float4* xr = (const float4*)(x + ((long)n * MN + m) * FI);
    float4 xv[8];
#pragma unroll
    for (int i = 0; i < 8; ++i) xv[i] = xr[i];
    const float* xf = (const float*)xv;

    float a0 = 0.f, a1 = 0.f;
#pragma unroll
    for (int k = 0; k < FI; ++k) {
        a0 += xf[k] * Ws[k * FO + 2 * j];
        a1 += xf[k] * Ws[k * FO + 2 * j + 1];
    }
    unsigned int lo = (unsigned int)__bfloat16_as_ushort(__float2bfloat16(a0));
    unsigned int hi = (unsigned int)__bfloat16_as_ushort(__float2bfloat16(a1));
    zb[(long)m * 128 + n * 16 + j] = lo | (hi << 16);
}

// ---------------- kernel 2: bin edges (col u16 | val-bf16 u16), 4 edges/thread ------
// Atomic-throughput-bound ~61us floor (invariant to thread count R5/R7, padding R9,
// and co-scheduling R10 -- runs alone so nothing contends with the atomic path).
__global__ __launch_bounds__(256) void fill_bucket(const int* __restrict__ rows,
                                                   const int* __restrict__ cols,
                                                   const float* __restrict__ vals,
                                                   int* __restrict__ cursor,
                                                   unsigned int* __restrict__ bucket) {
    int tid = blockIdx.x * 256 + threadIdx.x;
    if (tid >= FB_THREADS) return;   // grid rounds to 200192; avoid double edges
#pragma unroll
    for (int k = 0; k < 4; ++k) {
        int e = tid + k * FB_THREADS;   // covers [0, NE) exactly once
        int r = rows[e];
        int p = atomicAdd(&cursor[r], 1);
        if (p < CAP) {                  // overflow guard (never taken in practice)
            unsigned int vb = (unsigned int)__bfloat16_as_ushort(__float2bfloat16(vals[e]));
            bucket[(r << CAPLOG) + p] = (unsigned int)cols[e] | (vb << 16);
        }
    }
}

// ---------------- kernel 3 (R7-proven, 61us): one row per WAVE ----------------
// Block = 256 = 4 waves = 4 rows. Lane t: n = t>>3, float4 fo-group fp = t&7.
// Per edge: broadcast packed (col,val) via __shfl, gather 8 B/lane (512 B/wave).
__global__ __launch_bounds__(256) void aggregate(const unsigned long long* __restrict__ zb2,
                                                 const int* __restrict__ cursor,
                                                 const unsigned int* __restrict__ bucket,
                                                 const float* __restrict__ bias,
                                                 float4* __restrict__ out4) {
    int lane = threadIdx.x & 63;
    int r    = blockIdx.x * 4 + (threadIdx.x >> 6);

    int cnt = cursor[r];
    cnt = cnt > CAP ? CAP : cnt;

    unsigned int mypk = bucket[(r << CAPLOG) + lane];  // whole bucket row in-register

    int n  = lane >> 3;
    int fp = lane & 7;
    float4 acc = ((const float4*)bias)[fp];

    int i = 0;
    for (; i + 8 <= cnt; i += 8) {
        unsigned int pk[8];
        unsigned long long z[8];
#pragma unroll
        for (int k = 0; k < 8; ++k) pk[k] = __shfl(mypk, i + k);
#pragma unroll
        for (int k = 0; k < 8; ++k) z[k] = zb2[((long)(pk[k] & 0xffff) << 6) + lane];
#pragma unroll
        for (int k = 0; k < 8; ++k) {
            float v = __uint_as_float(pk[k] & 0xffff0000u);
            unsigned int l = (unsigned int)z[k], h = (unsigned int)(z[k] >> 32);
            acc.x += v * __uint_as_float(l << 16);
            acc.y += v * __uint_as_float(l & 0xffff0000u);
            acc.z += v * __uint_as_float(h << 16);
            acc.w += v * __uint_as_float(h & 0xffff0000u);
        }
    }
    for (; i + 4 <= cnt; i += 4) {
        unsigned int pk[4];
        unsigned long long z[4];
#pragma unroll
        for (int k = 0; k < 4; ++k) pk[k] = __shfl(mypk, i + k);
#pragma unroll
        for (int k = 0; k < 4; ++k) z[k] = zb2[((long)(pk[k] & 0xffff) << 6) + lane];
#pragma unroll
        for (int k = 0; k < 4; ++k) {
            float v = __uint_as_float(pk[k] & 0xffff0000u);
            unsigned int l = (unsigned int)z[k], h = (unsigned int)(z[k] >> 32);
            acc.x += v * __uint_as_float(l << 16);
            acc.y += v * __uint_as_float(l & 0xffff0000u);
            acc.z += v * __uint_as_float(h << 16);
            acc.w += v * __uint_as_float(h & 0xffff0000u);
        }
    }
    for (; i < cnt; ++i) {
        unsigned int p0 = __shfl(mypk, i);
        float v0 = __uint_as_float(p0 & 0xffff0000u);
        unsigned long long z0 = zb2[((long)(p0 & 0xffff) << 6) + lane];
        unsigned int l0 = (unsigned int)z0, h0 = (unsigned int)(z0 >> 32);
        acc.x += v0 * __uint_as_float(l0 << 16);
        acc.y += v0 * __uint_as_float(l0 & 0xffff0000u);
        acc.z += v0 * __uint_as_float(h0 << 16);
        acc.w += v0 * __uint_as_float(h0 & 0xffff0000u);
    }

    out4[((long)n * MN + r) * 8 + fp] = acc;
}

extern "C" void kernel_launch(void* const* d_in, const int* in_sizes, int n_in,
                              void* d_out, int out_size, void* d_ws, size_t ws_size,
                              hipStream_t stream) {
    const float* x    = (const float*)d_in[0];
    const int*   rows = (const int*)d_in[1];
    const int*   cols = (const int*)d_in[2];
    const float* vals = (const float*)d_in[3];
    const float* W    = (const float*)d_in[4];
    const float* bias = (const float*)d_in[5];
    float4* out4 = (float4*)d_out;

    char* ws = (char*)d_ws;
    // workspace layout (bytes): zb 25.6MB | cursor 0.2MB | bucket 12.8MB = 38.6MB
    size_t off_z      = 0;
    size_t off_cursor = off_z + (size_t)MN * NB * FO * 2;
    size_t off_bucket = off_cursor + (size_t)MN * 4;

    unsigned int* zb     = (unsigned int*)(ws + off_z);
    int*          cursor = (int*)(ws + off_cursor);
    unsigned int* bucket = (unsigned int*)(ws + off_bucket);

    gemm_xw<<<25000, 256, 0, stream>>>(x, W, zb, cursor);

    fill_bucket<<<FB_BLOCKS, 256, 0, stream>>>(rows, cols, vals, cursor, bucket);

    aggregate<<<MN / 4, 256, 0, stream>>>((const unsigned long long*)zb, cursor, bucket,
                                          bias, out4);
}

// Round 12
// 120.237 us; speedup vs baseline: 1.3318x; 1.2480x over previous
//
#include <hip/hip_runtime.h>
#include <hip/hip_bf16.h>

#define NB 8
#define MN 50000
#define FI 32
#define FO 32
#define NE 800000
#define CAPLOG 6          // 64 slots/row; P(Poisson(16) > 64) ~ 1e-19 per row
#define CAP 64
#define NBINS 196         // bin = row >> 8 (256 rows/bin); 196*256 = 50176 >= MN
#define BINCAPLOG 13      // 8192 edges/bin capacity = mean 4082 + 64 sigma

// ---------------- kernel 1: gemm + gCursor init ----------------
// z interleaved bf16x2: u32 zb[m*128 + n*16 + j] -> one edge's gather = 512 B
// contiguous (R7-proven layout). Block 0 also inits the 196 bin cursors.
__global__ __launch_bounds__(256) void gemm_xw(const float* __restrict__ x,
                                               const float* __restrict__ W,
                                               unsigned int* __restrict__ zb,
                                               int* __restrict__ gCursor) {
    int bid = blockIdx.x;
    int t   = threadIdx.x;

    if (bid == 0 && t < NBINS) gCursor[t] = t << BINCAPLOG;

    __shared__ float Ws[FI * FO];
    ((float4*)Ws)[t] = ((const float4*)W)[t];   // 256 * 16B = 4KB
    __syncthreads();

    int n     = bid / 3125;                 // 0..7
    int mb    = bid % 3125;
    int rowid = t >> 4;                     // 16 rows per block
    int j     = t & 15;                     // fo pair
    int m     = mb * 16 + rowid;

    const float4* xr = (const float4*)(x + ((long)n * MN + m) * FI);
    float4 xv[8];
#pragma unroll
    for (int i = 0; i < 8; ++i) xv[i] = xr[i];
    const float* xf = (const float*)xv;

    float a0 = 0.f, a1 = 0.f;
#pragma unroll
    for (int k = 0; k < FI; ++k) {
        a0 += xf[k] * Ws[k * FO + 2 * j];
        a1 += xf[k] * Ws[k * FO + 2 * j + 1];
    }
    unsigned int lo = (unsigned int)__bfloat16_as_ushort(__float2bfloat16(a0));
    unsigned int hi = (unsigned int)__bfloat16_as_ushort(__float2bfloat16(a1));
    zb[(long)m * 128 + n * 16 + j] = lo | (hi << 16);
}

// ---------------- kernel 2: coarse-bin edges (row>>8) into sorted runs -------------
// R11 diagnosis: old fill_bucket was write-allocate-bound (800k random 4B stores ->
// 47 MB line traffic). Here: LDS histogram + ONE global atomic per (block,bin)
// (~38k total) reserves contiguous runs -> writes are coalesced u64 runs.
// Payload: row<<32 | val_bf16<<16 | col (low 32 bits == bucket entry format).
__global__ __launch_bounds__(256) void bin_edges(const int* __restrict__ rows,
                                                 const int* __restrict__ cols,
                                                 const float* __restrict__ vals,
                                                 int* __restrict__ gCursor,
                                                 unsigned long long* __restrict__ sorted) {
    __shared__ int cnt[NBINS];
    __shared__ int base[NBINS];
    int t = threadIdx.x;
    for (int i = t; i < NBINS; i += 256) cnt[i] = 0;
    __syncthreads();

    unsigned long long pk[8];
    int bn[8], rk[8];
    int e0 = blockIdx.x * 2048;
#pragma unroll
    for (int k = 0; k < 8; ++k) {
        int e = e0 + k * 256 + t;
        bn[k] = -1;
        if (e < NE) {
            int r = rows[e];
            unsigned int vb = (unsigned int)__bfloat16_as_ushort(__float2bfloat16(vals[e]));
            pk[k] = ((unsigned long long)(unsigned int)r << 32) |
                    (unsigned long long)((vb << 16) | (unsigned int)cols[e]);
            bn[k] = r >> 8;
            rk[k] = atomicAdd(&cnt[bn[k]], 1);
        }
    }
    __syncthreads();
    if (t < NBINS) base[t] = atomicAdd(&gCursor[t], cnt[t]);
    __syncthreads();
#pragma unroll
    for (int k = 0; k < 8; ++k) {
        if (bn[k] >= 0) {
            int pos = base[bn[k]] + rk[k];
            if (pos < ((bn[k] + 1) << BINCAPLOG))   // capacity guard (64 sigma)
                sorted[pos] = pk[k];
        }
    }
}

// ---------------- kernel 3: per-bin bucket fill, LDS cursors only ------------------
// One block per bin (256 rows). LDS atomics assign slots (no global round-trips);
// bucket writes stay in the bin's 128 KB region (L2-resident -> full-line
// write-back, ~13 MB total). cursor[] written coalesced at the end (no memset).
__global__ __launch_bounds__(1024) void fill_sorted(const unsigned long long* __restrict__ sorted,
                                                    const int* __restrict__ gCursor,
                                                    unsigned int* __restrict__ bucket,
                                                    int* __restrict__ cursor) {
    __shared__ int cur[256];
    int t   = threadIdx.x;
    int bin = blockIdx.x;
    if (t < 256) cur[t] = 0;
    __syncthreads();

    int beg = bin << BINCAPLOG;
    int cnt = gCursor[bin] - beg;
    if (cnt > (1 << BINCAPLOG)) cnt = (1 << BINCAPLOG);

    for (int i = t; i < cnt; i += 1024) {
        unsigned long long pk = sorted[beg + i];
        int r  = (int)(pk >> 32);
        int lr = r & 255;
        int p  = atomicAdd(&cur[lr], 1);
        if (p < CAP)                       // overflow guard (never taken in practice)
            bucket[((long)r << CAPLOG) + p] = (unsigned int)pk;
    }
    __syncthreads();
    if (t < 256) {
        int R = (bin << 8) + t;
        if (R < MN) cursor[R] = cur[t] > CAP ? CAP : cur[t];
    }
}

// ---------------- kernel 4 (R7-proven, ~62us): one row per WAVE ----------------
// Block = 256 = 4 waves = 4 rows. Lane t: n = t>>3, float4 fo-group fp = t&7.
// Per edge: broadcast packed (col,val) via __shfl, gather 8 B/lane (512 B/wave).
__global__ __launch_bounds__(256) void aggregate(const unsigned long long* __restrict__ zb2,
                                                 const int* __restrict__ cursor,
                                                 const unsigned int* __restrict__ bucket,
                                                 const float* __restrict__ bias,
                                                 float4* __restrict__ out4) {
    int lane = threadIdx.x & 63;
    int r    = blockIdx.x * 4 + (threadIdx.x >> 6);

    int cnt = cursor[r];
    cnt = cnt > CAP ? CAP : cnt;

    unsigned int mypk = bucket[(r << CAPLOG) + lane];  // whole bucket row in-register

    int n  = lane >> 3;
    int fp = lane & 7;
    float4 acc = ((const float4*)bias)[fp];

    int i = 0;
    for (; i + 8 <= cnt; i += 8) {
        unsigned int pk[8];
        unsigned long long z[8];
#pragma unroll
        for (int k = 0; k < 8; ++k) pk[k] = __shfl(mypk, i + k);
#pragma unroll
        for (int k = 0; k < 8; ++k) z[k] = zb2[((long)(pk[k] & 0xffff) << 6) + lane];
#pragma unroll
        for (int k = 0; k < 8; ++k) {
            float v = __uint_as_float(pk[k] & 0xffff0000u);
            unsigned int l = (unsigned int)z[k], h = (unsigned int)(z[k] >> 32);
            acc.x += v * __uint_as_float(l << 16);
            acc.y += v * __uint_as_float(l & 0xffff0000u);
            acc.z += v * __uint_as_float(h << 16);
            acc.w += v * __uint_as_float(h & 0xffff0000u);
        }
    }
    for (; i + 4 <= cnt; i += 4) {
        unsigned int pk[4];
        unsigned long long z[4];
#pragma unroll
        for (int k = 0; k < 4; ++k) pk[k] = __shfl(mypk, i + k);
#pragma unroll
        for (int k = 0; k < 4; ++k) z[k] = zb2[((long)(pk[k] & 0xffff) << 6) + lane];
#pragma unroll
        for (int k = 0; k < 4; ++k) {
            float v = __uint_as_float(pk[k] & 0xffff0000u);
            unsigned int l = (unsigned int)z[k], h = (unsigned int)(z[k] >> 32);
            acc.x += v * __uint_as_float(l << 16);
            acc.y += v * __uint_as_float(l & 0xffff0000u);
            acc.z += v * __uint_as_float(h << 16);
            acc.w += v * __uint_as_float(h & 0xffff0000u);
        }
    }
    for (; i < cnt; ++i) {
        unsigned int p0 = __shfl(mypk, i);
        float v0 = __uint_as_float(p0 & 0xffff0000u);
        unsigned long long z0 = zb2[((long)(p0 & 0xffff) << 6) + lane];
        unsigned int l0 = (unsigned int)z0, h0 = (unsigned int)(z0 >> 32);
        acc.x += v0 * __uint_as_float(l0 << 16);
        acc.y += v0 * __uint_as_float(l0 & 0xffff0000u);
        acc.z += v0 * __uint_as_float(h0 << 16);
        acc.w += v0 * __uint_as_float(h0 & 0xffff0000u);
    }

    out4[((long)n * MN + r) * 8 + fp] = acc;
}

extern "C" void kernel_launch(void* const* d_in, const int* in_sizes, int n_in,
                              void* d_out, int out_size, void* d_ws, size_t ws_size,
                              hipStream_t stream) {
    const float* x    = (const float*)d_in[0];
    const int*   rows = (const int*)d_in[1];
    const int*   cols = (const int*)d_in[2];
    const float* vals = (const float*)d_in[3];
    const float* W    = (const float*)d_in[4];
    const float* bias = (const float*)d_in[5];
    float4* out4 = (float4*)d_out;

    char* ws = (char*)d_ws;
    // workspace (bytes): zb 25.6MB | cursor 0.2MB | gCursor 1KB | bucket 12.8MB |
    //                    sorted 12.8MB  = ~51.4MB
    size_t off_z      = 0;
    size_t off_cursor = off_z + (size_t)MN * NB * FO * 2;
    size_t off_gcur   = off_cursor + (size_t)MN * 4;
    size_t off_bucket = off_gcur + 1024;
    size_t off_sorted = off_bucket + (size_t)MN * CAP * 4;

    unsigned int*       zb      = (unsigned int*)(ws + off_z);
    int*                cursor  = (int*)(ws + off_cursor);
    int*                gCursor = (int*)(ws + off_gcur);
    unsigned int*       bucket  = (unsigned int*)(ws + off_bucket);
    unsigned long long* sorted  = (unsigned long long*)(ws + off_sorted);

    gemm_xw<<<25000, 256, 0, stream>>>(x, W, zb, gCursor);

    bin_edges<<<392, 256, 0, stream>>>(rows, cols, vals, gCursor, sorted);

    fill_sorted<<<NBINS, 1024, 0, stream>>>(sorted, gCursor, bucket, cursor);

    aggregate<<<MN / 4, 256, 0, stream>>>((const unsigned long long*)zb, cursor, bucket,
                                          bias, out4);
}